// Round 1
// baseline (5130.521 us; speedup 1.0000x reference)
//
#include <hip/hip_runtime.h>
#include <cstddef>

// Problem constants
#define kB 32
#define kT 2048
#define kIn 512
#define kH 256
#define kBeta 0.85f
#define kThr 1.0f

// ---------------------------------------------------------------------------
// Kernel 1: proj = x @ W_in^T + b_in
//   x: (M=65536, K=512) row-major, W_in: (N=256, K=512) row-major
//   out P: (M, 256) row-major  (written into d_out; consumed+overwritten by scan)
// Classic fp32 LDS-tiled GEMM: 128x128 tile, BK=16, 256 threads, 8x8 micro-tile.
// ---------------------------------------------------------------------------
#define BM 128
#define BN 128
#define BK 16
#define LDA (BM + 4)   // +4 pad: keeps 16B alignment of rows AND breaks 4-way
#define LDB (BN + 4)   // bank conflicts on the transposed staging stores

__global__ void __launch_bounds__(256)
gemm_proj(const float* __restrict__ A,     // x
          const float* __restrict__ W,     // W_in
          const float* __restrict__ bias,  // b_in
          float* __restrict__ P)
{
    __shared__ float As[BK * LDA];
    __shared__ float Bs[BK * LDB];
    const int tid = threadIdx.x;
    const int bm = blockIdx.x * BM;
    const int bn = blockIdx.y * BN;
    const int tx = tid & 15;   // n-direction
    const int ty = tid >> 4;   // m-direction

    float acc[8][8];
#pragma unroll
    for (int i = 0; i < 8; ++i)
#pragma unroll
        for (int j = 0; j < 8; ++j) acc[i][j] = 0.f;

    // staging chunk mapping: 512 float4 chunks per tile, 2 per thread
    const int c0 = tid, c1 = tid + 256;
    const int r0 = c0 >> 2, kc0 = (c0 & 3) << 2;
    const int r1 = c1 >> 2, kc1 = (c1 & 3) << 2;

    for (int kb = 0; kb < kIn; kb += BK) {
        const float4 a0v = *reinterpret_cast<const float4*>(A + (size_t)(bm + r0) * kIn + kb + kc0);
        const float4 a1v = *reinterpret_cast<const float4*>(A + (size_t)(bm + r1) * kIn + kb + kc1);
        const float4 b0v = *reinterpret_cast<const float4*>(W + (size_t)(bn + r0) * kIn + kb + kc0);
        const float4 b1v = *reinterpret_cast<const float4*>(W + (size_t)(bn + r1) * kIn + kb + kc1);
        __syncthreads();   // previous iteration's LDS reads done
        As[(kc0 + 0) * LDA + r0] = a0v.x;
        As[(kc0 + 1) * LDA + r0] = a0v.y;
        As[(kc0 + 2) * LDA + r0] = a0v.z;
        As[(kc0 + 3) * LDA + r0] = a0v.w;
        As[(kc1 + 0) * LDA + r1] = a1v.x;
        As[(kc1 + 1) * LDA + r1] = a1v.y;
        As[(kc1 + 2) * LDA + r1] = a1v.z;
        As[(kc1 + 3) * LDA + r1] = a1v.w;
        Bs[(kc0 + 0) * LDB + r0] = b0v.x;
        Bs[(kc0 + 1) * LDB + r0] = b0v.y;
        Bs[(kc0 + 2) * LDB + r0] = b0v.z;
        Bs[(kc0 + 3) * LDB + r0] = b0v.w;
        Bs[(kc1 + 0) * LDB + r1] = b1v.x;
        Bs[(kc1 + 1) * LDB + r1] = b1v.y;
        Bs[(kc1 + 2) * LDB + r1] = b1v.z;
        Bs[(kc1 + 3) * LDB + r1] = b1v.w;
        __syncthreads();

#pragma unroll
        for (int k = 0; k < BK; ++k) {
            const float4 aa0 = *reinterpret_cast<const float4*>(&As[k * LDA + ty * 4]);
            const float4 aa1 = *reinterpret_cast<const float4*>(&As[k * LDA + ty * 4 + 64]);
            const float4 bb0 = *reinterpret_cast<const float4*>(&Bs[k * LDB + tx * 4]);
            const float4 bb1 = *reinterpret_cast<const float4*>(&Bs[k * LDB + tx * 4 + 64]);
            const float av[8] = {aa0.x, aa0.y, aa0.z, aa0.w, aa1.x, aa1.y, aa1.z, aa1.w};
            const float bv[8] = {bb0.x, bb0.y, bb0.z, bb0.w, bb1.x, bb1.y, bb1.z, bb1.w};
#pragma unroll
            for (int i = 0; i < 8; ++i)
#pragma unroll
                for (int j = 0; j < 8; ++j)
                    acc[i][j] = fmaf(av[i], bv[j], acc[i][j]);
        }
    }

    // epilogue: + b_in, coalesced float4 stores
    const float4 bl = *reinterpret_cast<const float4*>(bias + bn + tx * 4);
    const float4 bh = *reinterpret_cast<const float4*>(bias + bn + tx * 4 + 64);
#pragma unroll
    for (int i = 0; i < 8; ++i) {
        const int m = bm + ty * 4 + (i & 3) + ((i >> 2) << 6);
        float4 o0, o1;
        o0.x = acc[i][0] + bl.x; o0.y = acc[i][1] + bl.y;
        o0.z = acc[i][2] + bl.z; o0.w = acc[i][3] + bl.w;
        o1.x = acc[i][4] + bh.x; o1.y = acc[i][5] + bh.y;
        o1.z = acc[i][6] + bh.z; o1.w = acc[i][7] + bh.w;
        *reinterpret_cast<float4*>(P + (size_t)m * kH + bn + tx * 4) = o0;
        *reinterpret_cast<float4*>(P + (size_t)m * kH + bn + tx * 4 + 64) = o1;
    }
}

// ---------------------------------------------------------------------------
// Kernel 2: sequential RLeaky scan. One workgroup per batch element (batches
// are independent; intra-batch all-to-all via V stays workgroup-local).
// Thread h owns neuron h: mem[h], spk[h], and row V[h][0..255] in 256 VGPRs
// (V = 256 KB fp32 doesn't fit in 160 KB LDS). Spikes exchanged per step via
// an LDS double buffer with ONE barrier per step.
//
// Algebra note: reset == (mem_prev > 1) == spk_prev exactly, but we keep the
// reference's op order (+ spk ... - reset*THR) verbatim with fp contraction
// off, because the output is binary spikes and any rounding-induced flip
// fails the absmax check.
//
// PO = proj (input) AND spike output: thread h reads proj[b,t,h] once, then
// overwrites the same address with the spike — no workspace needed.
// ---------------------------------------------------------------------------
__global__ void __launch_bounds__(256, 1)
scan_rleaky(float* __restrict__ PO,        // (B,T,H): proj in / spikes out
            const float* __restrict__ V,   // (H,H) row-major
            const float* __restrict__ brec)
{
    const int b = blockIdx.x;
    const int h = threadIdx.x;

    __shared__ float sspk[2][kH];

    // V row into registers (one-time, uncoalesced but tiny: 8 MB total)
    float4 Vr[kH / 4];
    const float4* Vrow = reinterpret_cast<const float4*>(V + (size_t)h * kH);
#pragma unroll
    for (int c = 0; c < kH / 4; ++c) Vr[c] = Vrow[c];

    const float br = brec[h];
    float mem = 0.f, spk = 0.f;
    sspk[0][h] = 0.f;

    float* base = PO + (size_t)b * kT * kH + h;

    for (int t = 0; t < kT; ++t) {
        __syncthreads();   // spikes of step t-1 visible in sspk[t&1]

        const float p = base[(size_t)t * kH];   // issue early; matvec hides latency

        // rec = V[h,:] . spk_prev  (spk_prev broadcast-read from LDS as float4)
        const float4* sp = reinterpret_cast<const float4*>(sspk[t & 1]);
        float a0 = 0.f, a1 = 0.f, a2 = 0.f, a3 = 0.f;
#pragma unroll
        for (int c = 0; c < kH / 4; ++c) {
            const float4 s = sp[c];
            const float4 v = Vr[c];
            a0 = fmaf(s.x, v.x, a0);
            a1 = fmaf(s.y, v.y, a1);
            a2 = fmaf(s.z, v.z, a2);
            a3 = fmaf(s.w, v.w, a3);
        }
        const float rec = ((a0 + a1) + (a2 + a3)) + br;

        float m2;
        {
#pragma clang fp contract(off)
            const float input_ = p + spk;            // combined = proj + spk
            m2 = kBeta * mem;                        // separate mul (match np)
            m2 = m2 + input_;
            m2 = m2 + rec;
            m2 = m2 - spk * kThr;                    // reset == spk_prev
        }
        const float ns = (m2 > kThr) ? 1.0f : 0.0f;  // spike_fn(mem - THR)

        base[(size_t)t * kH] = ns;                   // overwrite proj with spike
        sspk[(t + 1) & 1][h] = ns;                   // publish for step t+1
        mem = m2;
        spk = ns;
    }
}

// ---------------------------------------------------------------------------
extern "C" void kernel_launch(void* const* d_in, const int* in_sizes, int n_in,
                              void* d_out, int out_size, void* d_ws, size_t ws_size,
                              hipStream_t stream) {
    const float* x     = (const float*)d_in[0];
    const float* W_in  = (const float*)d_in[1];
    const float* b_in  = (const float*)d_in[2];
    const float* V     = (const float*)d_in[3];
    const float* b_rec = (const float*)d_in[4];
    float* out = (float*)d_out;

    dim3 g1((kB * kT) / BM, kH / BN);            // 512 x 2
    gemm_proj<<<g1, 256, 0, stream>>>(x, W_in, b_in, out);
    scan_rleaky<<<kB, 256, 0, stream>>>(out, V, b_rec);
}

// Round 2
// 4091.803 us; speedup vs baseline: 1.2539x; 1.2539x over previous
//
#include <hip/hip_runtime.h>
#include <cstddef>
#include <cstdint>

// Problem constants
#define kB 32
#define kT 2048
#define kIn 512
#define kH 256
#define kBeta 0.85f
#define kThr 1.0f

// ---------------------------------------------------------------------------
// Kernel 1: proj = x @ W_in^T + b_in   (unchanged from round 1: ~360 us)
// ---------------------------------------------------------------------------
#define BM 128
#define BN 128
#define BK 16
#define LDA (BM + 4)
#define LDB (BN + 4)

__global__ void __launch_bounds__(256)
gemm_proj(const float* __restrict__ A,
          const float* __restrict__ W,
          const float* __restrict__ bias,
          float* __restrict__ P)
{
    __shared__ float As[BK * LDA];
    __shared__ float Bs[BK * LDB];
    const int tid = threadIdx.x;
    const int bm = blockIdx.x * BM;
    const int bn = blockIdx.y * BN;
    const int tx = tid & 15;
    const int ty = tid >> 4;

    float acc[8][8];
#pragma unroll
    for (int i = 0; i < 8; ++i)
#pragma unroll
        for (int j = 0; j < 8; ++j) acc[i][j] = 0.f;

    const int c0 = tid, c1 = tid + 256;
    const int r0 = c0 >> 2, kc0 = (c0 & 3) << 2;
    const int r1 = c1 >> 2, kc1 = (c1 & 3) << 2;

    for (int kb = 0; kb < kIn; kb += BK) {
        const float4 a0v = *reinterpret_cast<const float4*>(A + (size_t)(bm + r0) * kIn + kb + kc0);
        const float4 a1v = *reinterpret_cast<const float4*>(A + (size_t)(bm + r1) * kIn + kb + kc1);
        const float4 b0v = *reinterpret_cast<const float4*>(W + (size_t)(bn + r0) * kIn + kb + kc0);
        const float4 b1v = *reinterpret_cast<const float4*>(W + (size_t)(bn + r1) * kIn + kb + kc1);
        __syncthreads();
        As[(kc0 + 0) * LDA + r0] = a0v.x;
        As[(kc0 + 1) * LDA + r0] = a0v.y;
        As[(kc0 + 2) * LDA + r0] = a0v.z;
        As[(kc0 + 3) * LDA + r0] = a0v.w;
        As[(kc1 + 0) * LDA + r1] = a1v.x;
        As[(kc1 + 1) * LDA + r1] = a1v.y;
        As[(kc1 + 2) * LDA + r1] = a1v.z;
        As[(kc1 + 3) * LDA + r1] = a1v.w;
        Bs[(kc0 + 0) * LDB + r0] = b0v.x;
        Bs[(kc0 + 1) * LDB + r0] = b0v.y;
        Bs[(kc0 + 2) * LDB + r0] = b0v.z;
        Bs[(kc0 + 3) * LDB + r0] = b0v.w;
        Bs[(kc1 + 0) * LDB + r1] = b1v.x;
        Bs[(kc1 + 1) * LDB + r1] = b1v.y;
        Bs[(kc1 + 2) * LDB + r1] = b1v.z;
        Bs[(kc1 + 3) * LDB + r1] = b1v.w;
        __syncthreads();

#pragma unroll
        for (int k = 0; k < BK; ++k) {
            const float4 aa0 = *reinterpret_cast<const float4*>(&As[k * LDA + ty * 4]);
            const float4 aa1 = *reinterpret_cast<const float4*>(&As[k * LDA + ty * 4 + 64]);
            const float4 bb0 = *reinterpret_cast<const float4*>(&Bs[k * LDB + tx * 4]);
            const float4 bb1 = *reinterpret_cast<const float4*>(&Bs[k * LDB + tx * 4 + 64]);
            const float av[8] = {aa0.x, aa0.y, aa0.z, aa0.w, aa1.x, aa1.y, aa1.z, aa1.w};
            const float bv[8] = {bb0.x, bb0.y, bb0.z, bb0.w, bb1.x, bb1.y, bb1.z, bb1.w};
#pragma unroll
            for (int i = 0; i < 8; ++i)
#pragma unroll
                for (int j = 0; j < 8; ++j)
                    acc[i][j] = fmaf(av[i], bv[j], acc[i][j]);
        }
    }

    const float4 bl = *reinterpret_cast<const float4*>(bias + bn + tx * 4);
    const float4 bh = *reinterpret_cast<const float4*>(bias + bn + tx * 4 + 64);
#pragma unroll
    for (int i = 0; i < 8; ++i) {
        const int m = bm + ty * 4 + (i & 3) + ((i >> 2) << 6);
        float4 o0, o1;
        o0.x = acc[i][0] + bl.x; o0.y = acc[i][1] + bl.y;
        o0.z = acc[i][2] + bl.z; o0.w = acc[i][3] + bl.w;
        o1.x = acc[i][4] + bh.x; o1.y = acc[i][5] + bh.y;
        o1.z = acc[i][6] + bh.z; o1.w = acc[i][7] + bh.w;
        *reinterpret_cast<float4*>(P + (size_t)m * kH + bn + tx * 4) = o0;
        *reinterpret_cast<float4*>(P + (size_t)m * kH + bn + tx * 4 + 64) = o1;
    }
}

// ---------------------------------------------------------------------------
// Kernel 2: scan, bitmask edition.
//   1024 threads/WG = (h = tid&255, q = tid>>8). Thread (h,q) holds
//   V[h][64q..64q+64) in 64 VGPRs and computes a 64-term partial dot per step
//   by unpacking the 64-bit spike ballot of wave q (3 VALU/bit, exact since
//   spikes are {0,1}: fma(1,V,acc)==acc+V, fma(0,V,acc)==acc).
//   Spike exchange: __ballot on owner waves -> 4 x u64 in LDS (32 B/step
//   instead of 1 KB/thread of float broadcasts). Two barriers per step.
//   Owner (q==0) threads keep mem/spk state, do the mem update, and:
//     - defer the global spike store by one step (hides vmcnt drain)
//     - burst-load proj 8 steps ahead into registers (one drain per 8 steps)
// ---------------------------------------------------------------------------
#define TBURST 8

__global__ void __launch_bounds__(1024, 4)
scan_rleaky(float* __restrict__ PO,        // (B,T,H): proj in / spikes out
            const float* __restrict__ V,   // (H,H) row-major
            const float* __restrict__ brec)
{
    const int b = blockIdx.x;
    const int tid = threadIdx.x;
    const int h = tid & (kH - 1);
    const int q = tid >> 8;                 // 0..3  (waves 0-3 <=> q==0)
    const bool owner = (q == 0);

    __shared__ unsigned long long smask[4];
    __shared__ float pbuf[kH * 4];          // partials, layout [h*4 + q]

    // V slice into registers (one-time)
    float Vr[64];
    {
        const float4* vp = reinterpret_cast<const float4*>(V + (size_t)h * kH + (q << 6));
#pragma unroll
        for (int c = 0; c < 16; ++c) {
            const float4 v = vp[c];
            Vr[c * 4 + 0] = v.x; Vr[c * 4 + 1] = v.y;
            Vr[c * 4 + 2] = v.z; Vr[c * 4 + 3] = v.w;
        }
    }

    const float br = owner ? brec[h] : 0.f;
    float mem = 0.f, spk = 0.f, prev_ns = 0.f;
    float* base = PO + (size_t)b * (size_t)kT * kH + h;

    if (tid < 4) smask[tid] = 0ull;

    // proj burst buffers (owner waves only issue the loads)
    float pb[TBURST], pb2[TBURST];
    if (owner) {
#pragma unroll
        for (int i = 0; i < TBURST; ++i) pb[i] = base[(size_t)i * kH];
    }
    __syncthreads();                         // zeros in smask visible

    for (int tb = 0; tb < kT / TBURST; ++tb) {
#pragma unroll
        for (int ti = 0; ti < TBURST; ++ti) {
            const int t = tb * TBURST + ti;

            // ---- phase 1 (all threads): partial dot from ballot mask ----
            if (owner) {
                if (t > 0) base[(size_t)(t - 1) * kH] = prev_ns;  // deferred store
                if (ti == 0) {                                    // next burst
#pragma unroll
                    for (int i = 0; i < TBURST; ++i) {
                        size_t tt = (size_t)(tb + 1) * TBURST + i;
                        if (tt > kT - 1) tt = kT - 1;             // clamp (harmless)
                        pb2[i] = base[tt * kH];
                    }
                }
            }

            const unsigned long long m = smask[q];
            const uint32_t lo = (uint32_t)m;
            const uint32_t hi = (uint32_t)(m >> 32);
            float a0 = 0.f, a1 = 0.f, a2 = 0.f, a3 = 0.f;
#pragma unroll
            for (int j = 0; j < 16; ++j)
                a0 = fmaf((float)((lo >> j) & 1u), Vr[j], a0);
#pragma unroll
            for (int j = 16; j < 32; ++j)
                a1 = fmaf((float)((lo >> j) & 1u), Vr[j], a1);
#pragma unroll
            for (int j = 0; j < 16; ++j)
                a2 = fmaf((float)((hi >> j) & 1u), Vr[32 + j], a2);
#pragma unroll
            for (int j = 16; j < 32; ++j)
                a3 = fmaf((float)((hi >> j) & 1u), Vr[32 + j], a3);
            pbuf[(h << 2) | q] = (a0 + a1) + (a2 + a3);

            __syncthreads();   // barrier A: partials visible

            // ---- phase 2 (owner waves): reduce + membrane update ----
            if (owner) {
                const float4 pp = reinterpret_cast<const float4*>(pbuf)[h];
                const float rec = ((pp.x + pp.y) + (pp.z + pp.w)) + br;
                const float p = pb[ti];
                float m2;
                {
#pragma clang fp contract(off)
                    const float input_ = p + spk;   // combined = proj + spk
                    m2 = kBeta * mem;               // keep reference op order
                    m2 = m2 + input_;
                    m2 = m2 + rec;
                    m2 = m2 - spk * kThr;           // reset == spk_prev exactly
                }
                const bool fire = (m2 > kThr);
                const float ns = fire ? 1.0f : 0.0f;
                const unsigned long long bm = __ballot(fire);
                if ((tid & 63) == 0) smask[tid >> 6] = bm;
                mem = m2;
                spk = ns;
                prev_ns = ns;
            }

            __syncthreads();   // barrier B: new mask visible
        }
        // rotate burst buffers (register moves)
        if (owner) {
#pragma unroll
            for (int i = 0; i < TBURST; ++i) pb[i] = pb2[i];
        }
    }

    if (owner) base[(size_t)(kT - 1) * kH] = prev_ns;  // final spike
}

// ---------------------------------------------------------------------------
extern "C" void kernel_launch(void* const* d_in, const int* in_sizes, int n_in,
                              void* d_out, int out_size, void* d_ws, size_t ws_size,
                              hipStream_t stream) {
    const float* x     = (const float*)d_in[0];
    const float* W_in  = (const float*)d_in[1];
    const float* b_in  = (const float*)d_in[2];
    const float* V     = (const float*)d_in[3];
    const float* b_rec = (const float*)d_in[4];
    float* out = (float*)d_out;

    dim3 g1((kB * kT) / BM, kH / BN);            // 512 x 2
    gemm_proj<<<g1, 256, 0, stream>>>(x, W_in, b_in, out);
    scan_rleaky<<<kB, 1024, 0, stream>>>(out, V, b_rec);
}

// Round 3
// 3222.215 us; speedup vs baseline: 1.5922x; 1.2699x over previous
//
#include <hip/hip_runtime.h>
#include <cstddef>
#include <cstdint>

// Problem constants
#define kB 32
#define kT 2048
#define kIn 512
#define kH 256
#define kBeta 0.85f
#define kThr 1.0f

// Fused-kernel layout: blocks [0, N_SCAN) = scan (one per batch),
// blocks [N_SCAN, N_SCAN+N_GEMM) = GEMM tiles (256x256, t-major order).
#define N_SCAN kB
#define N_GEMM (kB * 8)        // 32 b x 8 t_tiles (256 rows each)
#define FLAGS_PER_B 8
#define TBURST 8

// GEMM tile config: 256x256 tile, BK=16, 1024 threads, 8x8 micro-tile.
#define GBM 256
#define GBK 16
#define GLDA 260               // +4 pad: conflict-free transposed staging
#define SMEM_FLOATS (2 * GBK * GLDA)   // 8320 floats = 33.3 KB

__device__ __forceinline__ void wait_flag(int* f) {
    // acquire/agent: later proj loads must see the producer XCD's stores
    while (__hip_atomic_load(f, __ATOMIC_ACQUIRE, __HIP_MEMORY_SCOPE_AGENT) == 0) {
        __builtin_amdgcn_s_sleep(2);
    }
}

// ---------------------------------------------------------------------------
// GEMM body: proj tile = x(256xK) @ W_in^T(Kx256) + b_in, then publish flag.
// Per-element k-summation order is identical to rounds 1/2 (bit-identical proj).
// ---------------------------------------------------------------------------
__device__ void gemm_body(const float* __restrict__ A,
                          const float* __restrict__ W,
                          const float* __restrict__ bias,
                          float* __restrict__ P,
                          int* flags, int gid, float* smem)
{
    float* As = smem;
    float* Bs = smem + GBK * GLDA;
    const int tid = threadIdx.x;
    const int b  = gid & 31;          // t-major tile order: all b at t_tile 0 first
    const int tt = gid >> 5;          // 0..7
    const int bm = b * kT + tt * GBM; // row offset in flattened (B*T)
    const int tx = tid & 31;
    const int ty = tid >> 5;          // 0..31

    float acc[8][8];
#pragma unroll
    for (int i = 0; i < 8; ++i)
#pragma unroll
        for (int j = 0; j < 8; ++j) acc[i][j] = 0.f;

    // staging: 1024 float4 chunks per 256x16 tile; 1 A-chunk + 1 B-chunk per thread
    const int r = tid >> 2, kc = (tid & 3) << 2;

    for (int kb = 0; kb < kIn; kb += GBK) {
        const float4 av = *reinterpret_cast<const float4*>(A + (size_t)(bm + r) * kIn + kb + kc);
        const float4 bv = *reinterpret_cast<const float4*>(W + (size_t)r * kIn + kb + kc);
        __syncthreads();   // previous iteration's LDS reads done
        As[(kc + 0) * GLDA + r] = av.x;
        As[(kc + 1) * GLDA + r] = av.y;
        As[(kc + 2) * GLDA + r] = av.z;
        As[(kc + 3) * GLDA + r] = av.w;
        Bs[(kc + 0) * GLDA + r] = bv.x;
        Bs[(kc + 1) * GLDA + r] = bv.y;
        Bs[(kc + 2) * GLDA + r] = bv.z;
        Bs[(kc + 3) * GLDA + r] = bv.w;
        __syncthreads();

#pragma unroll
        for (int k = 0; k < GBK; ++k) {
            const float4 aa0 = *reinterpret_cast<const float4*>(&As[k * GLDA + ty * 4]);
            const float4 aa1 = *reinterpret_cast<const float4*>(&As[k * GLDA + ty * 4 + 128]);
            const float4 bb0 = *reinterpret_cast<const float4*>(&Bs[k * GLDA + tx * 4]);
            const float4 bb1 = *reinterpret_cast<const float4*>(&Bs[k * GLDA + tx * 4 + 128]);
            const float av8[8] = {aa0.x, aa0.y, aa0.z, aa0.w, aa1.x, aa1.y, aa1.z, aa1.w};
            const float bv8[8] = {bb0.x, bb0.y, bb0.z, bb0.w, bb1.x, bb1.y, bb1.z, bb1.w};
#pragma unroll
            for (int i = 0; i < 8; ++i)
#pragma unroll
                for (int j = 0; j < 8; ++j)
                    acc[i][j] = fmaf(av8[i], bv8[j], acc[i][j]);
        }
    }

    const float4 bl = *reinterpret_cast<const float4*>(bias + tx * 4);
    const float4 bh = *reinterpret_cast<const float4*>(bias + tx * 4 + 128);
#pragma unroll
    for (int i = 0; i < 8; ++i) {
        const int m = bm + ty * 4 + (i & 3) + ((i >> 2) << 7);
        float4 o0, o1;
        o0.x = acc[i][0] + bl.x; o0.y = acc[i][1] + bl.y;
        o0.z = acc[i][2] + bl.z; o0.w = acc[i][3] + bl.w;
        o1.x = acc[i][4] + bh.x; o1.y = acc[i][5] + bh.y;
        o1.z = acc[i][6] + bh.z; o1.w = acc[i][7] + bh.w;
        *reinterpret_cast<float4*>(P + (size_t)m * kH + tx * 4) = o0;
        *reinterpret_cast<float4*>(P + (size_t)m * kH + tx * 4 + 128) = o1;
    }

    __syncthreads();   // all stores executed block-wide
    if (flags && tid == 0) {
        __threadfence();                                  // device-scope release
        atomicAdd(flags + b * FLAGS_PER_B + tt, 1);       // publish (b, tt) ready
    }
}

// ---------------------------------------------------------------------------
// Scan body: bitmask spikes, wave-uniform mask forced scalar (readfirstlane)
// so bit extraction rides the SALU pipe: 2 VALU/bit (v_cvt + v_fmac).
// Structure (burst prefetch, deferred store, 2 barriers/step) as round 2;
// fp accumulation order bit-identical to round 2.
// ---------------------------------------------------------------------------
__device__ void scan_body(float* __restrict__ PO,
                          const float* __restrict__ V,
                          const float* __restrict__ brec,
                          int* flags, float* smem)
{
    unsigned long long* smask = reinterpret_cast<unsigned long long*>(smem);
    float* pbuf = smem + 8;     // [kH*4] partials, layout [h*4 + q]

    const int b = blockIdx.x;
    const int tid = threadIdx.x;
    const int h = tid & (kH - 1);
    const int q = tid >> 8;     // 0..3; waves 0-3 <=> q==0 (owners)
    const bool owner = (q == 0);

    float Vr[64];
    {
        const float4* vp = reinterpret_cast<const float4*>(V + (size_t)h * kH + (q << 6));
#pragma unroll
        for (int c = 0; c < 16; ++c) {
            const float4 v = vp[c];
            Vr[c * 4 + 0] = v.x; Vr[c * 4 + 1] = v.y;
            Vr[c * 4 + 2] = v.z; Vr[c * 4 + 3] = v.w;
        }
    }

    const float br = owner ? brec[h] : 0.f;
    float mem = 0.f, spk = 0.f, prev_ns = 0.f;
    float* base = PO + (size_t)b * (size_t)kT * kH + h;

    if (tid < 4) smask[tid] = 0ull;

    int* bflags = flags ? (flags + b * FLAGS_PER_B) : nullptr;

    float pb[TBURST], pb2[TBURST];
    if (owner) {
        if (bflags) wait_flag(bflags + 0);     // proj tile (b, t<256) ready
#pragma unroll
        for (int i = 0; i < TBURST; ++i) pb[i] = base[(size_t)i * kH];
    }
    __syncthreads();

    for (int tb = 0; tb < kT / TBURST; ++tb) {
#pragma unroll
        for (int ti = 0; ti < TBURST; ++ti) {
            const int t = tb * TBURST + ti;

            if (owner) {
                if (t > 0) base[(size_t)(t - 1) * kH] = prev_ns;   // deferred store
                if (ti == 0) {
                    const int nb = tb + 1;
                    if (bflags && nb < (kT / TBURST) && (nb & 31) == 0)
                        wait_flag(bflags + (nb >> 5));             // next 256-step tile
#pragma unroll
                    for (int i = 0; i < TBURST; ++i) {
                        int tt2 = nb * TBURST + i;
                        if (tt2 > kT - 1) tt2 = kT - 1;            // clamp (harmless)
                        pb2[i] = base[(size_t)tt2 * kH];
                    }
                }
            }

            // mask is wave-uniform (q uniform per wave) -> force SGPR
            const unsigned long long m = smask[q];
            const uint32_t lo = __builtin_amdgcn_readfirstlane((uint32_t)m);
            const uint32_t hi = __builtin_amdgcn_readfirstlane((uint32_t)(m >> 32));
            float a0 = 0.f, a1 = 0.f, a2 = 0.f, a3 = 0.f;
#pragma unroll
            for (int j = 0; j < 16; ++j)
                a0 = fmaf((float)((lo >> j) & 1u), Vr[j], a0);
#pragma unroll
            for (int j = 16; j < 32; ++j)
                a1 = fmaf((float)((lo >> j) & 1u), Vr[j], a1);
#pragma unroll
            for (int j = 0; j < 16; ++j)
                a2 = fmaf((float)((hi >> j) & 1u), Vr[32 + j], a2);
#pragma unroll
            for (int j = 16; j < 32; ++j)
                a3 = fmaf((float)((hi >> j) & 1u), Vr[32 + j], a3);
            pbuf[(h << 2) | q] = (a0 + a1) + (a2 + a3);

            __syncthreads();   // barrier A: partials visible

            if (owner) {
                const float4 pp = reinterpret_cast<const float4*>(pbuf)[h];
                const float rec = ((pp.x + pp.y) + (pp.z + pp.w)) + br;
                const float p = pb[ti];
                float m2;
                {
#pragma clang fp contract(off)
                    const float input_ = p + spk;   // combined = proj + spk
                    m2 = kBeta * mem;               // reference op order
                    m2 = m2 + input_;
                    m2 = m2 + rec;
                    m2 = m2 - spk * kThr;           // reset == spk_prev exactly
                }
                const bool fire = (m2 > kThr);
                const float ns = fire ? 1.0f : 0.0f;
                const unsigned long long bm = __ballot(fire);
                if ((tid & 63) == 0) smask[tid >> 6] = bm;
                mem = m2;
                spk = ns;
                prev_ns = ns;
            }

            __syncthreads();   // barrier B: new mask visible
        }
        if (owner) {
#pragma unroll
            for (int i = 0; i < TBURST; ++i) pb[i] = pb2[i];
        }
    }

    if (owner) base[(size_t)(kT - 1) * kH] = prev_ns;
}

// ---------------------------------------------------------------------------
// Fused kernel. Scan blocks first (typically dispatched first -> grab CUs and
// spin on flags); GEMM blocks fill the remaining 224+ CUs. Deadlock-free under
// ANY dispatch order: GEMM never waits, and only 32 scan blocks exist so GEMM
// blocks always have free CUs.
// ---------------------------------------------------------------------------
__global__ void __launch_bounds__(1024, 4)
fused(const float* __restrict__ x, const float* __restrict__ W,
      const float* __restrict__ b_in, const float* __restrict__ V,
      const float* __restrict__ b_rec, float* __restrict__ PO,
      int* flags, int n_scan)
{
    __shared__ __align__(16) float smem[SMEM_FLOATS];
    if ((int)blockIdx.x < n_scan) {
        scan_body(PO, V, b_rec, flags, smem);
    } else {
        gemm_body(x, W, b_in, PO, flags, (int)blockIdx.x - n_scan, smem);
    }
}

// ---------------------------------------------------------------------------
extern "C" void kernel_launch(void* const* d_in, const int* in_sizes, int n_in,
                              void* d_out, int out_size, void* d_ws, size_t ws_size,
                              hipStream_t stream) {
    const float* x     = (const float*)d_in[0];
    const float* W_in  = (const float*)d_in[1];
    const float* b_in  = (const float*)d_in[2];
    const float* V     = (const float*)d_in[3];
    const float* b_rec = (const float*)d_in[4];
    float* out = (float*)d_out;

    const size_t flag_bytes = (size_t)N_SCAN * FLAGS_PER_B * sizeof(int);
    if (ws_size >= flag_bytes) {
        int* flags = (int*)d_ws;
        hipMemsetAsync(flags, 0, flag_bytes, stream);   // ws is poisoned 0xAA
        fused<<<N_SCAN + N_GEMM, 1024, 0, stream>>>(x, W_in, b_in, V, b_rec,
                                                    out, flags, N_SCAN);
    } else {
        // fallback: sequential (no flags) — GEMM pass, then scan pass
        fused<<<N_GEMM, 1024, 0, stream>>>(x, W_in, b_in, V, b_rec, out, nullptr, 0);
        fused<<<N_SCAN, 1024, 0, stream>>>(x, W_in, b_in, V, b_rec, out, nullptr, N_SCAN);
    }
}

// Round 4
// 1778.161 us; speedup vs baseline: 2.8853x; 1.8121x over previous
//
#include <hip/hip_runtime.h>
#include <cstddef>
#include <cstdint>

// Problem constants
#define kB 32
#define kT 2048
#define kIn 512
#define kH 256
#define kBeta 0.85f
#define kThr 1.0f

// Fused-kernel layout: blocks [0, N_SCAN) = scan (one per batch),
// blocks [N_SCAN, N_SCAN+N_GEMM) = GEMM tiles (256x256, t-major order).
#define N_SCAN kB
#define N_GEMM (kB * 8)        // 32 b x 8 t_tiles (256 rows each)
#define FLAGS_PER_B 8
#define TBURST 8

// GEMM tile config: 256x256 tile, BK=16, 1024 threads, 8x8 micro-tile.
#define GBM 256
#define GBK 16
#define GLDA 260               // +4 pad: conflict-free transposed staging
#define SMEM_FLOATS (2 * GBK * GLDA)   // 8320 floats = 33.3 KB (>= scan's 16.7 KB)

// scan pbuf row stride (floats): pbuf[w*SSTRIDE + h], 1040 B rows (16B-aligned)
#define SSTRIDE 260

__device__ __forceinline__ void wait_flag(int* f) {
    // acquire/agent: later proj loads must see the producer XCD's stores
    while (__hip_atomic_load(f, __ATOMIC_ACQUIRE, __HIP_MEMORY_SCOPE_AGENT) == 0) {
        __builtin_amdgcn_s_sleep(2);
    }
}

// ---------------------------------------------------------------------------
// GEMM body: proj tile = x(256xK) @ W_in^T(Kx256) + b_in, then publish flag.
// Per-element k-summation order identical to rounds 1-3 (bit-identical proj).
// ---------------------------------------------------------------------------
__device__ void gemm_body(const float* __restrict__ A,
                          const float* __restrict__ W,
                          const float* __restrict__ bias,
                          float* __restrict__ P,
                          int* flags, int gid, float* smem)
{
    float* As = smem;
    float* Bs = smem + GBK * GLDA;
    const int tid = threadIdx.x;
    const int b  = gid & 31;          // t-major tile order: all b at t_tile 0 first
    const int tt = gid >> 5;          // 0..7
    const int bm = b * kT + tt * GBM; // row offset in flattened (B*T)
    const int tx = tid & 31;
    const int ty = tid >> 5;          // 0..31

    float acc[8][8];
#pragma unroll
    for (int i = 0; i < 8; ++i)
#pragma unroll
        for (int j = 0; j < 8; ++j) acc[i][j] = 0.f;

    const int r = tid >> 2, kc = (tid & 3) << 2;

    for (int kb = 0; kb < kIn; kb += GBK) {
        const float4 av = *reinterpret_cast<const float4*>(A + (size_t)(bm + r) * kIn + kb + kc);
        const float4 bv = *reinterpret_cast<const float4*>(W + (size_t)r * kIn + kb + kc);
        __syncthreads();   // previous iteration's LDS reads done
        As[(kc + 0) * GLDA + r] = av.x;
        As[(kc + 1) * GLDA + r] = av.y;
        As[(kc + 2) * GLDA + r] = av.z;
        As[(kc + 3) * GLDA + r] = av.w;
        Bs[(kc + 0) * GLDA + r] = bv.x;
        Bs[(kc + 1) * GLDA + r] = bv.y;
        Bs[(kc + 2) * GLDA + r] = bv.z;
        Bs[(kc + 3) * GLDA + r] = bv.w;
        __syncthreads();

#pragma unroll
        for (int k = 0; k < GBK; ++k) {
            const float4 aa0 = *reinterpret_cast<const float4*>(&As[k * GLDA + ty * 4]);
            const float4 aa1 = *reinterpret_cast<const float4*>(&As[k * GLDA + ty * 4 + 128]);
            const float4 bb0 = *reinterpret_cast<const float4*>(&Bs[k * GLDA + tx * 4]);
            const float4 bb1 = *reinterpret_cast<const float4*>(&Bs[k * GLDA + tx * 4 + 128]);
            const float av8[8] = {aa0.x, aa0.y, aa0.z, aa0.w, aa1.x, aa1.y, aa1.z, aa1.w};
            const float bv8[8] = {bb0.x, bb0.y, bb0.z, bb0.w, bb1.x, bb1.y, bb1.z, bb1.w};
#pragma unroll
            for (int i = 0; i < 8; ++i)
#pragma unroll
                for (int j = 0; j < 8; ++j)
                    acc[i][j] = fmaf(av8[i], bv8[j], acc[i][j]);
        }
    }

    const float4 bl = *reinterpret_cast<const float4*>(bias + tx * 4);
    const float4 bh = *reinterpret_cast<const float4*>(bias + tx * 4 + 128);
#pragma unroll
    for (int i = 0; i < 8; ++i) {
        const int m = bm + ty * 4 + (i & 3) + ((i >> 2) << 7);
        float4 o0, o1;
        o0.x = acc[i][0] + bl.x; o0.y = acc[i][1] + bl.y;
        o0.z = acc[i][2] + bl.z; o0.w = acc[i][3] + bl.w;
        o1.x = acc[i][4] + bh.x; o1.y = acc[i][5] + bh.y;
        o1.z = acc[i][6] + bh.z; o1.w = acc[i][7] + bh.w;
        *reinterpret_cast<float4*>(P + (size_t)m * kH + tx * 4) = o0;
        *reinterpret_cast<float4*>(P + (size_t)m * kH + tx * 4 + 128) = o1;
    }

    __syncthreads();   // all stores executed block-wide
    if (flags && tid == 0) {
        __threadfence();                                  // device-scope release
        atomicAdd(flags + b * FLAGS_PER_B + tt, 1);       // publish (b, tt) ready
    }
}

// ---------------------------------------------------------------------------
// Scan body, round 4: 16-way k-split + nibble-skip.
//   wave w (0..15), lane l: handles h in {4l..4l+3}, k in [16w, 16w+16).
//   Each wave's 16 mask bits are scalar (readfirstlane); per bit: 1 v_cvt
//   shared by 4 v_fmac (one per h-row) -> unpack tax amortized 4x.
//   All-zero nibbles skipped via scalar branch (exact: fmaf(0,.,acc)==acc).
//   Partials: one ds_write_b128 per thread -> pbuf[w*260 + 4l]; owner thread
//   h (tid<256) sums the 16 w-partials in a fixed tree, then does the
//   membrane update verbatim (same fp sequence as rounds 1-3).
// ---------------------------------------------------------------------------
__device__ void scan_body(float* __restrict__ PO,
                          const float* __restrict__ V,
                          const float* __restrict__ brec,
                          int* flags, float* smem)
{
    unsigned long long* smask = reinterpret_cast<unsigned long long*>(smem);
    float* pbuf = smem + 16;    // 64B offset; pbuf[w*SSTRIDE + h], 16 rows

    const int b = blockIdx.x;
    const int tid = threadIdx.x;
    const int w = tid >> 6;         // wave 0..15 = k-chunk index
    const int l = tid & 63;
    const int h0 = l << 2;          // this thread's 4 h-rows: h0..h0+3
    const int kc = w << 4;          // k base
    const bool owner = (tid < kH);  // waves 0-3: per-neuron state owners
    const int h = tid & (kH - 1);

    // V regs: Vr[i][c] = V[h0+i][kc+c]   (64 VGPRs, one-time load)
    float Vr[4][16];
#pragma unroll
    for (int i = 0; i < 4; ++i) {
        const float4* vp = reinterpret_cast<const float4*>(V + (size_t)(h0 + i) * kH + kc);
#pragma unroll
        for (int c4 = 0; c4 < 4; ++c4) {
            const float4 v = vp[c4];
            Vr[i][c4 * 4 + 0] = v.x; Vr[i][c4 * 4 + 1] = v.y;
            Vr[i][c4 * 4 + 2] = v.z; Vr[i][c4 * 4 + 3] = v.w;
        }
    }

    const float br = owner ? brec[h] : 0.f;
    float mem = 0.f, spk = 0.f, prev_ns = 0.f;
    float* base = PO + (size_t)b * (size_t)kT * kH + h;

    if (tid < 4) smask[tid] = 0ull;

    int* bflags = flags ? (flags + b * FLAGS_PER_B) : nullptr;

    float pb[TBURST], pb2[TBURST];
    if (owner) {
        if (bflags) wait_flag(bflags + 0);     // proj tile (b, t<256) ready
#pragma unroll
        for (int i = 0; i < TBURST; ++i) pb[i] = base[(size_t)i * kH];
    }
    __syncthreads();

    const int mshift = (w & 3) << 4;           // 16-bit sub-chunk of the u64

    for (int tb = 0; tb < kT / TBURST; ++tb) {
#pragma unroll
        for (int ti = 0; ti < TBURST; ++ti) {
            const int t = tb * TBURST + ti;

            if (owner) {
                if (t > 0) base[(size_t)(t - 1) * kH] = prev_ns;   // deferred store
                if (ti == 0) {
                    const int nb = tb + 1;
                    if (bflags && nb < (kT / TBURST) && (nb & 31) == 0)
                        wait_flag(bflags + (nb >> 5));             // next 256-step tile
#pragma unroll
                    for (int i = 0; i < TBURST; ++i) {
                        int tt2 = nb * TBURST + i;
                        if (tt2 > kT - 1) tt2 = kT - 1;            // clamp (harmless)
                        pb2[i] = base[(size_t)tt2 * kH];
                    }
                }
            }

            // ---- phase 1: partial dots from this wave's 16 scalar mask bits
            const unsigned long long m = smask[w >> 2];
            const uint32_t chunk =
                __builtin_amdgcn_readfirstlane((uint32_t)(m >> mshift)) & 0xFFFFu;

            float a0 = 0.f, a1 = 0.f, a2 = 0.f, a3 = 0.f;
#pragma unroll
            for (int n = 0; n < 4; ++n) {
                const uint32_t nib = (chunk >> (n * 4)) & 0xFu;
                if (nib) {                       // scalar (wave-uniform) skip
#pragma unroll
                    for (int bit = 0; bit < 4; ++bit) {
                        const int j = n * 4 + bit;
                        const float bf = (float)((nib >> bit) & 1u);  // 1 cvt
                        a0 = fmaf(bf, Vr[0][j], a0);                  // 4 fmacs
                        a1 = fmaf(bf, Vr[1][j], a1);
                        a2 = fmaf(bf, Vr[2][j], a2);
                        a3 = fmaf(bf, Vr[3][j], a3);
                    }
                }
            }
            float4 part; part.x = a0; part.y = a1; part.z = a2; part.w = a3;
            *reinterpret_cast<float4*>(pbuf + w * SSTRIDE + h0) = part;

            __syncthreads();   // barrier A: partials visible

            // ---- phase 2 (owner waves): 16-way reduce + membrane update
            if (owner) {
                float s0  = pbuf[ 0 * SSTRIDE + h], s1  = pbuf[ 1 * SSTRIDE + h];
                float s2  = pbuf[ 2 * SSTRIDE + h], s3  = pbuf[ 3 * SSTRIDE + h];
                float s4  = pbuf[ 4 * SSTRIDE + h], s5  = pbuf[ 5 * SSTRIDE + h];
                float s6  = pbuf[ 6 * SSTRIDE + h], s7  = pbuf[ 7 * SSTRIDE + h];
                float s8  = pbuf[ 8 * SSTRIDE + h], s9  = pbuf[ 9 * SSTRIDE + h];
                float s10 = pbuf[10 * SSTRIDE + h], s11 = pbuf[11 * SSTRIDE + h];
                float s12 = pbuf[12 * SSTRIDE + h], s13 = pbuf[13 * SSTRIDE + h];
                float s14 = pbuf[14 * SSTRIDE + h], s15 = pbuf[15 * SSTRIDE + h];
                const float r0 = (s0 + s1) + (s2 + s3);
                const float r1 = (s4 + s5) + (s6 + s7);
                const float r2 = (s8 + s9) + (s10 + s11);
                const float r3 = (s12 + s13) + (s14 + s15);
                const float rec = ((r0 + r1) + (r2 + r3)) + br;
                const float p = pb[ti];
                float m2;
                {
#pragma clang fp contract(off)
                    const float input_ = p + spk;   // combined = proj + spk
                    m2 = kBeta * mem;               // reference op order
                    m2 = m2 + input_;
                    m2 = m2 + rec;
                    m2 = m2 - spk * kThr;           // reset == spk_prev exactly
                }
                const bool fire = (m2 > kThr);
                const float ns = fire ? 1.0f : 0.0f;
                const unsigned long long bm = __ballot(fire);
                if ((tid & 63) == 0) smask[tid >> 6] = bm;
                mem = m2;
                spk = ns;
                prev_ns = ns;
            }

            __syncthreads();   // barrier B: new mask visible
        }
        if (owner) {
#pragma unroll
            for (int i = 0; i < TBURST; ++i) pb[i] = pb2[i];
        }
    }

    if (owner) base[(size_t)(kT - 1) * kH] = prev_ns;
}

// ---------------------------------------------------------------------------
__global__ void __launch_bounds__(1024, 4)
fused(const float* __restrict__ x, const float* __restrict__ W,
      const float* __restrict__ b_in, const float* __restrict__ V,
      const float* __restrict__ b_rec, float* __restrict__ PO,
      int* flags, int n_scan)
{
    __shared__ __align__(16) float smem[SMEM_FLOATS];
    if ((int)blockIdx.x < n_scan) {
        scan_body(PO, V, b_rec, flags, smem);
    } else {
        gemm_body(x, W, b_in, PO, flags, (int)blockIdx.x - n_scan, smem);
    }
}

// ---------------------------------------------------------------------------
extern "C" void kernel_launch(void* const* d_in, const int* in_sizes, int n_in,
                              void* d_out, int out_size, void* d_ws, size_t ws_size,
                              hipStream_t stream) {
    const float* x     = (const float*)d_in[0];
    const float* W_in  = (const float*)d_in[1];
    const float* b_in  = (const float*)d_in[2];
    const float* V     = (const float*)d_in[3];
    const float* b_rec = (const float*)d_in[4];
    float* out = (float*)d_out;

    const size_t flag_bytes = (size_t)N_SCAN * FLAGS_PER_B * sizeof(int);
    if (ws_size >= flag_bytes) {
        int* flags = (int*)d_ws;
        hipMemsetAsync(flags, 0, flag_bytes, stream);   // ws is poisoned 0xAA
        fused<<<N_SCAN + N_GEMM, 1024, 0, stream>>>(x, W_in, b_in, V, b_rec,
                                                    out, flags, N_SCAN);
    } else {
        // fallback: sequential (no flags) — GEMM pass, then scan pass
        fused<<<N_GEMM, 1024, 0, stream>>>(x, W_in, b_in, V, b_rec, out, nullptr, 0);
        fused<<<N_SCAN, 1024, 0, stream>>>(x, W_in, b_in, V, b_rec, out, nullptr, N_SCAN);
    }
}

// Round 6
// 1750.057 us; speedup vs baseline: 2.9316x; 1.0161x over previous
//
#include <hip/hip_runtime.h>
#include <cstddef>
#include <cstdint>

// Problem constants
#define kB 32
#define kT 2048
#define kIn 512
#define kH 256
#define kBeta 0.85f
#define kThr 1.0f

// Fused-kernel layout: blocks [0, N_SCAN) = scan (one per batch),
// blocks [N_SCAN, N_SCAN+N_GEMM) = GEMM tiles (256x256, t-major order).
#define N_SCAN kB
#define N_GEMM (kB * 8)        // 32 b x 8 t_tiles (256 rows each)
#define FLAGS_PER_B 8
#define TBURST 8

// GEMM tile config: 256x256 tile, BK=16, 1024 threads, 8x8 micro-tile.
#define GBM 256
#define GBK 16
#define GLDA 260               // +4 pad: conflict-free transposed staging
#define SMEM_FLOATS (2 * GBK * GLDA)   // 8320 floats = 33.3 KB (>= scan's 16.7 KB)

// scan pbuf row stride (floats): pbuf[w*SSTRIDE + h], 1040 B rows (16B-aligned)
#define SSTRIDE 260

__device__ __forceinline__ void wait_flag(int* f) {
    // acquire/agent: later proj loads must see the producer XCD's stores
    while (__hip_atomic_load(f, __ATOMIC_ACQUIRE, __HIP_MEMORY_SCOPE_AGENT) == 0) {
        __builtin_amdgcn_s_sleep(2);
    }
}

// ---------------------------------------------------------------------------
// GEMM body: proj tile = x(256xK) @ W_in^T(Kx256) + b_in, then publish flag.
// Per-element k-summation order identical to rounds 1-4 (bit-identical proj).
// ---------------------------------------------------------------------------
__device__ void gemm_body(const float* __restrict__ A,
                          const float* __restrict__ W,
                          const float* __restrict__ bias,
                          float* __restrict__ P,
                          int* flags, int gid, float* smem)
{
    float* As = smem;
    float* Bs = smem + GBK * GLDA;
    const int tid = threadIdx.x;
    const int b  = gid & 31;          // t-major tile order: all b at t_tile 0 first
    const int tt = gid >> 5;          // 0..7
    const int bm = b * kT + tt * GBM; // row offset in flattened (B*T)
    const int tx = tid & 31;
    const int ty = tid >> 5;          // 0..31

    float acc[8][8];
#pragma unroll
    for (int i = 0; i < 8; ++i)
#pragma unroll
        for (int j = 0; j < 8; ++j) acc[i][j] = 0.f;

    const int r = tid >> 2, kc = (tid & 3) << 2;

    for (int kb = 0; kb < kIn; kb += GBK) {
        const float4 av = *reinterpret_cast<const float4*>(A + (size_t)(bm + r) * kIn + kb + kc);
        const float4 bv = *reinterpret_cast<const float4*>(W + (size_t)r * kIn + kb + kc);
        __syncthreads();   // previous iteration's LDS reads done
        As[(kc + 0) * GLDA + r] = av.x;
        As[(kc + 1) * GLDA + r] = av.y;
        As[(kc + 2) * GLDA + r] = av.z;
        As[(kc + 3) * GLDA + r] = av.w;
        Bs[(kc + 0) * GLDA + r] = bv.x;
        Bs[(kc + 1) * GLDA + r] = bv.y;
        Bs[(kc + 2) * GLDA + r] = bv.z;
        Bs[(kc + 3) * GLDA + r] = bv.w;
        __syncthreads();

#pragma unroll
        for (int k = 0; k < GBK; ++k) {
            const float4 aa0 = *reinterpret_cast<const float4*>(&As[k * GLDA + ty * 4]);
            const float4 aa1 = *reinterpret_cast<const float4*>(&As[k * GLDA + ty * 4 + 128]);
            const float4 bb0 = *reinterpret_cast<const float4*>(&Bs[k * GLDA + tx * 4]);
            const float4 bb1 = *reinterpret_cast<const float4*>(&Bs[k * GLDA + tx * 4 + 128]);
            const float av8[8] = {aa0.x, aa0.y, aa0.z, aa0.w, aa1.x, aa1.y, aa1.z, aa1.w};
            const float bv8[8] = {bb0.x, bb0.y, bb0.z, bb0.w, bb1.x, bb1.y, bb1.z, bb1.w};
#pragma unroll
            for (int i = 0; i < 8; ++i)
#pragma unroll
                for (int j = 0; j < 8; ++j)
                    acc[i][j] = fmaf(av8[i], bv8[j], acc[i][j]);
        }
    }

    const float4 bl = *reinterpret_cast<const float4*>(bias + tx * 4);
    const float4 bh = *reinterpret_cast<const float4*>(bias + tx * 4 + 128);
#pragma unroll
    for (int i = 0; i < 8; ++i) {
        const int m = bm + ty * 4 + (i & 3) + ((i >> 2) << 7);
        float4 o0, o1;
        o0.x = acc[i][0] + bl.x; o0.y = acc[i][1] + bl.y;
        o0.z = acc[i][2] + bl.z; o0.w = acc[i][3] + bl.w;
        o1.x = acc[i][4] + bh.x; o1.y = acc[i][5] + bh.y;
        o1.z = acc[i][6] + bh.z; o1.w = acc[i][7] + bh.w;
        *reinterpret_cast<float4*>(P + (size_t)m * kH + tx * 4) = o0;
        *reinterpret_cast<float4*>(P + (size_t)m * kH + tx * 4 + 128) = o1;
    }

    __syncthreads();   // all stores executed block-wide
    if (flags && tid == 0) {
        __threadfence();                                  // device-scope release
        atomicAdd(flags + b * FLAGS_PER_B + tt, 1);       // publish (b, tt) ready
    }
}

// ---------------------------------------------------------------------------
// Scan body, round 6: round-4 structure (known-good, absmax 0.0) with ONE
// change: spike stores buffered 8 steps in registers (sst) and issued at
// ti==0 together with the proj prefetch burst. Steps ti=1..7 then have zero
// outstanding vmem, so the per-barrier s_waitcnt vmcnt(0) drains nothing on
// 14 of 16 barriers per burst (the ~900-cyc store-retire latency that sat on
// every step's critical path in R4 now amortizes to ~110 cyc/step).
// All computed values are bit-identical to round 4.
// ---------------------------------------------------------------------------
__device__ void scan_body(float* __restrict__ PO,
                          const float* __restrict__ V,
                          const float* __restrict__ brec,
                          int* flags, float* smem)
{
    unsigned long long* smask = reinterpret_cast<unsigned long long*>(smem);
    float* pbuf = smem + 16;    // 64B offset; pbuf[w*SSTRIDE + h], 16 rows

    const int b = blockIdx.x;
    const int tid = threadIdx.x;
    const int w = tid >> 6;         // wave 0..15 = k-chunk index
    const int l = tid & 63;
    const int h0 = l << 2;          // this thread's 4 h-rows: h0..h0+3
    const int kc = w << 4;          // k base
    const bool owner = (tid < kH);  // waves 0-3: per-neuron state owners
    const int h = tid & (kH - 1);

    // V regs: Vr[i][c] = V[h0+i][kc+c]   (64 VGPRs, one-time load)
    float Vr[4][16];
#pragma unroll
    for (int i = 0; i < 4; ++i) {
        const float4* vp = reinterpret_cast<const float4*>(V + (size_t)(h0 + i) * kH + kc);
#pragma unroll
        for (int c4 = 0; c4 < 4; ++c4) {
            const float4 v = vp[c4];
            Vr[i][c4 * 4 + 0] = v.x; Vr[i][c4 * 4 + 1] = v.y;
            Vr[i][c4 * 4 + 2] = v.z; Vr[i][c4 * 4 + 3] = v.w;
        }
    }

    const float br = owner ? brec[h] : 0.f;
    float mem = 0.f, spk = 0.f;
    float* base = PO + (size_t)b * (size_t)kT * kH + h;

    if (tid < 4) smask[tid] = 0ull;

    int* bflags = flags ? (flags + b * FLAGS_PER_B) : nullptr;

    float pb[TBURST], pb2[TBURST], sst[TBURST];
    if (owner) {
        if (bflags) wait_flag(bflags + 0);     // proj tile (b, t<256) ready
#pragma unroll
        for (int i = 0; i < TBURST; ++i) pb[i] = base[(size_t)i * kH];
    }
    __syncthreads();

    const int mshift = (w & 3) << 4;           // 16-bit sub-chunk of the u64

    for (int tb = 0; tb < kT / TBURST; ++tb) {
#pragma unroll
        for (int ti = 0; ti < TBURST; ++ti) {

            // ---- vmem burst (owners, 1 step in 8): store last 8 spikes +
            //      prefetch next 8 proj rows. Steps ti=1..7 are vmem-clean.
            if (owner && ti == 0) {
                if (tb > 0) {
#pragma unroll
                    for (int i = 0; i < TBURST; ++i)
                        base[(size_t)((tb - 1) * TBURST + i) * kH] = sst[i];
                }
                const int nb = tb + 1;
                if (bflags && nb < (kT / TBURST) && (nb & 31) == 0)
                    wait_flag(bflags + (nb >> 5));             // next 256-step tile
#pragma unroll
                for (int i = 0; i < TBURST; ++i) {
                    int tt2 = nb * TBURST + i;
                    if (tt2 > kT - 1) tt2 = kT - 1;            // clamp (harmless)
                    pb2[i] = base[(size_t)tt2 * kH];
                }
            }

            // ---- phase 1: partial dots from this wave's 16 scalar mask bits
            const unsigned long long m = smask[w >> 2];
            const uint32_t chunk =
                __builtin_amdgcn_readfirstlane((uint32_t)(m >> mshift)) & 0xFFFFu;

            float a0 = 0.f, a1 = 0.f, a2 = 0.f, a3 = 0.f;
#pragma unroll
            for (int n = 0; n < 4; ++n) {
                const uint32_t nib = (chunk >> (n * 4)) & 0xFu;
                if (nib) {                       // scalar (wave-uniform) skip
#pragma unroll
                    for (int bit = 0; bit < 4; ++bit) {
                        const int j = n * 4 + bit;
                        const float bf = (float)((nib >> bit) & 1u);  // 1 cvt
                        a0 = fmaf(bf, Vr[0][j], a0);                  // 4 fmacs
                        a1 = fmaf(bf, Vr[1][j], a1);
                        a2 = fmaf(bf, Vr[2][j], a2);
                        a3 = fmaf(bf, Vr[3][j], a3);
                    }
                }
            }
            float4 part; part.x = a0; part.y = a1; part.z = a2; part.w = a3;
            *reinterpret_cast<float4*>(pbuf + w * SSTRIDE + h0) = part;

            __syncthreads();   // barrier A: partials visible

            // ---- phase 2 (owner waves): 16-way reduce + membrane update
            if (owner) {
                float s0  = pbuf[ 0 * SSTRIDE + h], s1  = pbuf[ 1 * SSTRIDE + h];
                float s2  = pbuf[ 2 * SSTRIDE + h], s3  = pbuf[ 3 * SSTRIDE + h];
                float s4  = pbuf[ 4 * SSTRIDE + h], s5  = pbuf[ 5 * SSTRIDE + h];
                float s6  = pbuf[ 6 * SSTRIDE + h], s7  = pbuf[ 7 * SSTRIDE + h];
                float s8  = pbuf[ 8 * SSTRIDE + h], s9  = pbuf[ 9 * SSTRIDE + h];
                float s10 = pbuf[10 * SSTRIDE + h], s11 = pbuf[11 * SSTRIDE + h];
                float s12 = pbuf[12 * SSTRIDE + h], s13 = pbuf[13 * SSTRIDE + h];
                float s14 = pbuf[14 * SSTRIDE + h], s15 = pbuf[15 * SSTRIDE + h];
                const float r0 = (s0 + s1) + (s2 + s3);
                const float r1 = (s4 + s5) + (s6 + s7);
                const float r2 = (s8 + s9) + (s10 + s11);
                const float r3 = (s12 + s13) + (s14 + s15);
                const float rec = ((r0 + r1) + (r2 + r3)) + br;
                const float p = pb[ti];
                float m2;
                {
#pragma clang fp contract(off)
                    const float input_ = p + spk;   // combined = proj + spk
                    m2 = kBeta * mem;               // reference op order
                    m2 = m2 + input_;
                    m2 = m2 + rec;
                    m2 = m2 - spk * kThr;           // reset == spk_prev exactly
                }
                const bool fire = (m2 > kThr);
                const float ns = fire ? 1.0f : 0.0f;
                const unsigned long long bm = __ballot(fire);
                if ((tid & 63) == 0) smask[tid >> 6] = bm;
                mem = m2;
                spk = ns;
                sst[ti] = ns;                       // buffered; stored next burst
            }

            __syncthreads();   // barrier B: new mask visible
        }
        if (owner) {
#pragma unroll
            for (int i = 0; i < TBURST; ++i) pb[i] = pb2[i];
        }
    }

    // final burst of spikes (t = kT-8 .. kT-1)
    if (owner) {
#pragma unroll
        for (int i = 0; i < TBURST; ++i)
            base[(size_t)((kT / TBURST - 1) * TBURST + i) * kH] = sst[i];
    }
}

// ---------------------------------------------------------------------------
__global__ void __launch_bounds__(1024, 4)
fused(const float* __restrict__ x, const float* __restrict__ W,
      const float* __restrict__ b_in, const float* __restrict__ V,
      const float* __restrict__ b_rec, float* __restrict__ PO,
      int* flags, int n_scan)
{
    __shared__ __align__(16) float smem[SMEM_FLOATS];
    if ((int)blockIdx.x < n_scan) {
        scan_body(PO, V, b_rec, flags, smem);
    } else {
        gemm_body(x, W, b_in, PO, flags, (int)blockIdx.x - n_scan, smem);
    }
}

// ---------------------------------------------------------------------------
extern "C" void kernel_launch(void* const* d_in, const int* in_sizes, int n_in,
                              void* d_out, int out_size, void* d_ws, size_t ws_size,
                              hipStream_t stream) {
    const float* x     = (const float*)d_in[0];
    const float* W_in  = (const float*)d_in[1];
    const float* b_in  = (const float*)d_in[2];
    const float* V     = (const float*)d_in[3];
    const float* b_rec = (const float*)d_in[4];
    float* out = (float*)d_out;

    const size_t flag_bytes = (size_t)N_SCAN * FLAGS_PER_B * sizeof(int);
    if (ws_size >= flag_bytes) {
        int* flags = (int*)d_ws;
        hipMemsetAsync(flags, 0, flag_bytes, stream);   // ws is poisoned 0xAA
        fused<<<N_SCAN + N_GEMM, 1024, 0, stream>>>(x, W_in, b_in, V, b_rec,
                                                    out, flags, N_SCAN);
    } else {
        // fallback: sequential (no flags) — GEMM pass, then scan pass
        fused<<<N_GEMM, 1024, 0, stream>>>(x, W_in, b_in, V, b_rec, out, nullptr, 0);
        fused<<<N_SCAN, 1024, 0, stream>>>(x, W_in, b_in, V, b_rec, out, nullptr, N_SCAN);
    }
}